// Round 1
// baseline (465.757 us; speedup 1.0000x reference)
//
#include <hip/hip_runtime.h>
#include <math.h>

// ---------------------------------------------------------------------------
// ComprehensiveGANLoss: scalar = feature_matching + musical + adversarial
// B=32, S=2048, P=128, D=512. Memory-bound: 553 MB read once.
//
// R4: occupancy/latency fix. R3 was grid-limited (1057 blocks -> ~12 waves/CU,
// OccupancyPercent 37%) with a ~1000-cycle dependent chain per b-iteration
// (loads -> 6-deep shfl_xor norm reduce -> rsqrt -> FMAs) and only unroll-2
// lookahead -> memory pipe idle, 3.4 TB/s effective.
// Now: one block per row (4225 blocks), the 32-b loop split across the 4
// waves (8 b's each, partial accumulators combined in LDS before squaring),
// plus an explicit 1-deep load double-buffer. 16.9k waves saturates the
// 32-waves/CU cap; __launch_bounds__(256,8) keeps VGPR<=64 for that cap.
// ---------------------------------------------------------------------------

#define B_ 32
#define S_ 2048
#define P_ 128
#define D_ 512

#define NT_LOCAL  S_                 // one task per s row
#define NT_INPUT  S_
#define NT_PHRASE P_
#define NTASK (NT_LOCAL + NT_INPUT + NT_PHRASE + 1)  // 4225

#define BPW (B_ / 4)                 // b's per wave = 8

__global__ void zero_out_kernel(float* out) {
    if (threadIdx.x == 0 && blockIdx.x == 0) out[0] = 0.0f;
}

__device__ __forceinline__ float sum8(float4 a, float4 b) {
    return a.x * a.x + a.y * a.y + a.z * a.z + a.w * a.w
         + b.x * b.x + b.y * b.y + b.z * b.z + b.w * b.w;
}

__global__ __launch_bounds__(256, 8) void fm_stream(
    const float* __restrict__ real_local, const float* __restrict__ real_phrase,
    const float* __restrict__ real_global, const float* __restrict__ real_input,
    const float* __restrict__ fake_local, const float* __restrict__ fake_phrase,
    const float* __restrict__ fake_global, const float* __restrict__ fake_input,
    float* __restrict__ out)
{
    const int task = blockIdx.x;
    const int w = threadIdx.x >> 6;       // wave id = b-subrange owner
    const int c = threadIdx.x & 63;       // lane: covers d=4c..4c+3 and 256+4c..

    const float* rp; const float* fp;
    long long rowBase;                    // float offset of this task's row
    long long rs4;                        // float4 stride between b-rows
    float scale;

    if (task < NT_LOCAL) {
        rp = real_local; fp = fake_local;
        rowBase = (long long)task * D_;
        rs4 = (long long)S_ * D_ / 4;
        scale = 0.4f / (4.0f * 1024.0f * (float)S_ * (float)D_);
    } else if (task < NT_LOCAL + NT_INPUT) {
        int t = task - NT_LOCAL;
        rp = real_input; fp = fake_input;
        rowBase = (long long)t * D_;
        rs4 = (long long)S_ * D_ / 4;
        scale = 0.1f / (4.0f * 1024.0f * (float)S_ * (float)D_);
    } else if (task < NT_LOCAL + NT_INPUT + NT_PHRASE) {
        int t = task - NT_LOCAL - NT_INPUT;
        rp = real_phrase; fp = fake_phrase;
        rowBase = (long long)t * D_;
        rs4 = (long long)P_ * D_ / 4;
        scale = 0.4f / (4.0f * 1024.0f * (float)P_ * (float)D_);
    } else {
        rp = real_global; fp = fake_global;
        rowBase = 0;
        rs4 = D_ / 4;
        scale = 0.2f / (4.0f * 1024.0f * (float)D_);
    }

    // This wave's first b-row (wave w owns b = w*8 .. w*8+7)
    const float4* rb = (const float4*)(rp + rowBase) + (long long)(w * BPW) * rs4;
    const float4* fb = (const float4*)(fp + rowBase) + (long long)(w * BPW) * rs4;

    float4 a0 = make_float4(0.f, 0.f, 0.f, 0.f);
    float4 a1 = make_float4(0.f, 0.f, 0.f, 0.f);

    // 1-deep double buffer: next b's 4 loads are in flight across the
    // shuffle-reduce chain of the current b.
    float4 x0 = rb[c], x1 = rb[64 + c];
    float4 y0 = fb[c], y1 = fb[64 + c];

    #pragma unroll
    for (int i = 0; i < BPW; ++i) {
        float4 nx0 = x0, nx1 = x1, ny0 = y0, ny1 = y1;
        if (i < BPW - 1) {
            rb += rs4; fb += rs4;
            nx0 = rb[c]; nx1 = rb[64 + c];
            ny0 = fb[c]; ny1 = fb[64 + c];
        }

        float ssr = sum8(x0, x1);
        float ssf = sum8(y0, y1);
        #pragma unroll
        for (int off = 1; off <= 32; off <<= 1) {
            ssr += __shfl_xor(ssr, off, 64);
            ssf += __shfl_xor(ssf, off, 64);
        }
        float ir = -1.0f / fmaxf(sqrtf(ssr), 1e-12f);
        float jf =  1.0f / fmaxf(sqrtf(ssf), 1e-12f);

        a0.x = fmaf(x0.x, ir, fmaf(y0.x, jf, a0.x));
        a0.y = fmaf(x0.y, ir, fmaf(y0.y, jf, a0.y));
        a0.z = fmaf(x0.z, ir, fmaf(y0.z, jf, a0.z));
        a0.w = fmaf(x0.w, ir, fmaf(y0.w, jf, a0.w));
        a1.x = fmaf(x1.x, ir, fmaf(y1.x, jf, a1.x));
        a1.y = fmaf(x1.y, ir, fmaf(y1.y, jf, a1.y));
        a1.z = fmaf(x1.z, ir, fmaf(y1.z, jf, a1.z));
        a1.w = fmaf(x1.w, ir, fmaf(y1.w, jf, a1.w));

        x0 = nx0; x1 = nx1; y0 = ny0; y1 = ny1;
    }

    // Cross-wave combine (sum over all 32 b) BEFORE squaring.
    // Layout [3][8][64]: lane-contiguous per slot -> conflict-free.
    __shared__ float wacc[3][8][64];
    if (w > 0) {
        int wi = w - 1;
        wacc[wi][0][c] = a0.x; wacc[wi][1][c] = a0.y;
        wacc[wi][2][c] = a0.z; wacc[wi][3][c] = a0.w;
        wacc[wi][4][c] = a1.x; wacc[wi][5][c] = a1.y;
        wacc[wi][6][c] = a1.z; wacc[wi][7][c] = a1.w;
    }
    __syncthreads();
    if (w == 0) {
        #pragma unroll
        for (int wi = 0; wi < 3; ++wi) {
            a0.x += wacc[wi][0][c]; a0.y += wacc[wi][1][c];
            a0.z += wacc[wi][2][c]; a0.w += wacc[wi][3][c];
            a1.x += wacc[wi][4][c]; a1.y += wacc[wi][5][c];
            a1.z += wacc[wi][6][c]; a1.w += wacc[wi][7][c];
        }
        float ssq = sum8(a0, a1);
        #pragma unroll
        for (int off = 1; off <= 32; off <<= 1)
            ssq += __shfl_xor(ssq, off, 64);
        if (c == 0) atomicAdd(out, ssq * scale);
    }
}

__device__ __forceinline__ float softplus_neg(float x) {
    float z = -x;
    return fmaxf(z, 0.0f) + log1pf(expf(-fabsf(z)));
}

__global__ __launch_bounds__(256) void small_kernel(
    const float* __restrict__ local_logits,
    const float* __restrict__ phrase_logits,
    const float* __restrict__ global_logits,
    const int* __restrict__ tokens,
    float* __restrict__ out)
{
    int gid = blockIdx.x * blockDim.x + threadIdx.x;
    float acc = 0.0f;

    const int NPAIR = B_ * (S_ - 1);  // 65504
    if (gid < NPAIR) {
        int b = gid / (S_ - 1);
        int j = gid - b * (S_ - 1);
        int t0 = tokens[b * S_ + j];
        int t1 = tokens[b * S_ + j + 1];
        float ts0 = (t0 >= 256 && t0 < 768) ? 1.0f : 0.0f;
        float ts1 = (t1 >= 256 && t1 < 768) ? 1.0f : 0.0f;
        float rhythm = fabsf(ts1 - ts0);
        int p0 = (t0 < 128) ? t0 : 0;
        int p1 = (t1 < 128) ? t1 : 0;
        int iv = abs(p0 % 12 - p1 % 12);
        float harsh = (iv == 6 || iv == 11) ? 1.0f : 0.0f;
        float mel = (abs(p1 - p0) > 12) ? 1.0f : 0.0f;
        acc += rhythm * (1.0f / (float)NPAIR)
             + harsh * (1.0f / ((float)B_ * (float)S_))
             + mel * (1.0f / (float)NPAIR);
    }

    if (gid < B_ * S_)   acc += 0.4f * softplus_neg(local_logits[gid])  / (float)(B_ * S_);
    if (gid < B_ * P_)   acc += 0.4f * softplus_neg(phrase_logits[gid]) / (float)(B_ * P_);
    if (gid < B_)        acc += 0.2f * softplus_neg(global_logits[gid]) / (float)B_;

    #pragma unroll
    for (int off = 32; off > 0; off >>= 1)
        acc += __shfl_xor(acc, off, 64);

    __shared__ float warp_sums[4];
    int wid = threadIdx.x >> 6;
    int lane = threadIdx.x & 63;
    if (lane == 0) warp_sums[wid] = acc;
    __syncthreads();
    if (threadIdx.x == 0) {
        float t = warp_sums[0] + warp_sums[1] + warp_sums[2] + warp_sums[3];
        atomicAdd(out, t);
    }
}

extern "C" void kernel_launch(void* const* d_in, const int* in_sizes, int n_in,
                              void* d_out, int out_size, void* d_ws, size_t ws_size,
                              hipStream_t stream) {
    const float* real_local   = (const float*)d_in[0];
    const float* real_phrase  = (const float*)d_in[1];
    const float* real_global  = (const float*)d_in[2];
    const float* real_input   = (const float*)d_in[3];
    const float* fake_local   = (const float*)d_in[4];
    const float* fake_phrase  = (const float*)d_in[5];
    const float* fake_global  = (const float*)d_in[6];
    const float* fake_input   = (const float*)d_in[7];
    const float* local_logits  = (const float*)d_in[8];
    const float* phrase_logits = (const float*)d_in[9];
    const float* global_logits = (const float*)d_in[10];
    const int*   tokens        = (const int*)d_in[11];
    float* out = (float*)d_out;

    zero_out_kernel<<<1, 64, 0, stream>>>(out);

    fm_stream<<<NTASK, 256, 0, stream>>>(
        real_local, real_phrase, real_global, real_input,
        fake_local, fake_phrase, fake_global, fake_input, out);

    small_kernel<<<(B_ * S_) / 256, 256, 0, stream>>>(
        local_logits, phrase_logits, global_logits, tokens, out);
}

// Round 5
// 449.076 us; speedup vs baseline: 1.0371x; 1.0371x over previous
//
#include <hip/hip_runtime.h>
#include <math.h>

// ---------------------------------------------------------------------------
// ComprehensiveGANLoss: scalar = feature_matching + musical + adversarial
// B=32, S=2048, P=128, D=512. Memory-bound: 553 MB read once.
//
// R5 (3rd resubmit; rounds 2-4 all died on infra: GPUAcquisitionTimeout x2,
// "container failed twice" x1 -- zero dispatches ran, hypothesis untested):
// non-temporal loads on the big streams. R4 fixed occupancy (37->81%)
// with ZERO time change; R1-R4 (four different access organizations) all
// plateau at 3.35-3.4 TB/s effective. FETCH_SIZE=277MB of 553MB shows half
// the traffic is L3 hits, half HBM -- yet neither pipe is saturated. Theory:
// the streaming footprint (2.1x L3) is allocated into Infinity Cache on
// every miss, so L3 SRAM pays hit-reads + miss-fills + evictions for all
// 553 MB -> ~3.4 TB/s combined choke. Non-temporal loads (global_load nt)
// skip cache allocation; all traffic should stream from HBM at ~6 TB/s.
// Structure otherwise identical to R4 (row-per-block, b-split across waves,
// 1-deep double buffer, LDS cross-wave combine).
// ---------------------------------------------------------------------------

#define B_ 32
#define S_ 2048
#define P_ 128
#define D_ 512

#define NT_LOCAL  S_                 // one task per s row
#define NT_INPUT  S_
#define NT_PHRASE P_
#define NTASK (NT_LOCAL + NT_INPUT + NT_PHRASE + 1)  // 4225

#define BPW (B_ / 4)                 // b's per wave = 8

typedef float vf4 __attribute__((ext_vector_type(4)));

__global__ void zero_out_kernel(float* out) {
    if (threadIdx.x == 0 && blockIdx.x == 0) out[0] = 0.0f;
}

__device__ __forceinline__ float4 ntload(const float4* p) {
    vf4 v = __builtin_nontemporal_load((const vf4*)p);
    return make_float4(v.x, v.y, v.z, v.w);
}

__device__ __forceinline__ float sum8(float4 a, float4 b) {
    return a.x * a.x + a.y * a.y + a.z * a.z + a.w * a.w
         + b.x * b.x + b.y * b.y + b.z * b.z + b.w * b.w;
}

__global__ __launch_bounds__(256, 8) void fm_stream(
    const float* __restrict__ real_local, const float* __restrict__ real_phrase,
    const float* __restrict__ real_global, const float* __restrict__ real_input,
    const float* __restrict__ fake_local, const float* __restrict__ fake_phrase,
    const float* __restrict__ fake_global, const float* __restrict__ fake_input,
    float* __restrict__ out)
{
    const int task = blockIdx.x;
    const int w = threadIdx.x >> 6;       // wave id = b-subrange owner
    const int c = threadIdx.x & 63;       // lane: covers d=4c..4c+3 and 256+4c..

    const float* rp; const float* fp;
    long long rowBase;                    // float offset of this task's row
    long long rs4;                        // float4 stride between b-rows
    float scale;

    if (task < NT_LOCAL) {
        rp = real_local; fp = fake_local;
        rowBase = (long long)task * D_;
        rs4 = (long long)S_ * D_ / 4;
        scale = 0.4f / (4.0f * 1024.0f * (float)S_ * (float)D_);
    } else if (task < NT_LOCAL + NT_INPUT) {
        int t = task - NT_LOCAL;
        rp = real_input; fp = fake_input;
        rowBase = (long long)t * D_;
        rs4 = (long long)S_ * D_ / 4;
        scale = 0.1f / (4.0f * 1024.0f * (float)S_ * (float)D_);
    } else if (task < NT_LOCAL + NT_INPUT + NT_PHRASE) {
        int t = task - NT_LOCAL - NT_INPUT;
        rp = real_phrase; fp = fake_phrase;
        rowBase = (long long)t * D_;
        rs4 = (long long)P_ * D_ / 4;
        scale = 0.4f / (4.0f * 1024.0f * (float)P_ * (float)D_);
    } else {
        rp = real_global; fp = fake_global;
        rowBase = 0;
        rs4 = D_ / 4;
        scale = 0.2f / (4.0f * 1024.0f * (float)D_);
    }

    // This wave's first b-row (wave w owns b = w*8 .. w*8+7)
    const float4* rb = (const float4*)(rp + rowBase) + (long long)(w * BPW) * rs4;
    const float4* fb = (const float4*)(fp + rowBase) + (long long)(w * BPW) * rs4;

    float4 a0 = make_float4(0.f, 0.f, 0.f, 0.f);
    float4 a1 = make_float4(0.f, 0.f, 0.f, 0.f);

    // 1-deep double buffer: next b's 4 loads are in flight across the
    // shuffle-reduce chain of the current b.
    float4 x0 = ntload(rb + c), x1 = ntload(rb + 64 + c);
    float4 y0 = ntload(fb + c), y1 = ntload(fb + 64 + c);

    #pragma unroll
    for (int i = 0; i < BPW; ++i) {
        float4 nx0 = x0, nx1 = x1, ny0 = y0, ny1 = y1;
        if (i < BPW - 1) {
            rb += rs4; fb += rs4;
            nx0 = ntload(rb + c); nx1 = ntload(rb + 64 + c);
            ny0 = ntload(fb + c); ny1 = ntload(fb + 64 + c);
        }

        float ssr = sum8(x0, x1);
        float ssf = sum8(y0, y1);
        #pragma unroll
        for (int off = 1; off <= 32; off <<= 1) {
            ssr += __shfl_xor(ssr, off, 64);
            ssf += __shfl_xor(ssf, off, 64);
        }
        float ir = -1.0f / fmaxf(sqrtf(ssr), 1e-12f);
        float jf =  1.0f / fmaxf(sqrtf(ssf), 1e-12f);

        a0.x = fmaf(x0.x, ir, fmaf(y0.x, jf, a0.x));
        a0.y = fmaf(x0.y, ir, fmaf(y0.y, jf, a0.y));
        a0.z = fmaf(x0.z, ir, fmaf(y0.z, jf, a0.z));
        a0.w = fmaf(x0.w, ir, fmaf(y0.w, jf, a0.w));
        a1.x = fmaf(x1.x, ir, fmaf(y1.x, jf, a1.x));
        a1.y = fmaf(x1.y, ir, fmaf(y1.y, jf, a1.y));
        a1.z = fmaf(x1.z, ir, fmaf(y1.z, jf, a1.z));
        a1.w = fmaf(x1.w, ir, fmaf(y1.w, jf, a1.w));

        x0 = nx0; x1 = nx1; y0 = ny0; y1 = ny1;
    }

    // Cross-wave combine (sum over all 32 b) BEFORE squaring.
    // Layout [3][8][64]: lane-contiguous per slot -> conflict-free.
    __shared__ float wacc[3][8][64];
    if (w > 0) {
        int wi = w - 1;
        wacc[wi][0][c] = a0.x; wacc[wi][1][c] = a0.y;
        wacc[wi][2][c] = a0.z; wacc[wi][3][c] = a0.w;
        wacc[wi][4][c] = a1.x; wacc[wi][5][c] = a1.y;
        wacc[wi][6][c] = a1.z; wacc[wi][7][c] = a1.w;
    }
    __syncthreads();
    if (w == 0) {
        #pragma unroll
        for (int wi = 0; wi < 3; ++wi) {
            a0.x += wacc[wi][0][c]; a0.y += wacc[wi][1][c];
            a0.z += wacc[wi][2][c]; a0.w += wacc[wi][3][c];
            a1.x += wacc[wi][4][c]; a1.y += wacc[wi][5][c];
            a1.z += wacc[wi][6][c]; a1.w += wacc[wi][7][c];
        }
        float ssq = sum8(a0, a1);
        #pragma unroll
        for (int off = 1; off <= 32; off <<= 1)
            ssq += __shfl_xor(ssq, off, 64);
        if (c == 0) atomicAdd(out, ssq * scale);
    }
}

__device__ __forceinline__ float softplus_neg(float x) {
    float z = -x;
    return fmaxf(z, 0.0f) + log1pf(expf(-fabsf(z)));
}

__global__ __launch_bounds__(256) void small_kernel(
    const float* __restrict__ local_logits,
    const float* __restrict__ phrase_logits,
    const float* __restrict__ global_logits,
    const int* __restrict__ tokens,
    float* __restrict__ out)
{
    int gid = blockIdx.x * blockDim.x + threadIdx.x;
    float acc = 0.0f;

    const int NPAIR = B_ * (S_ - 1);  // 65504
    if (gid < NPAIR) {
        int b = gid / (S_ - 1);
        int j = gid - b * (S_ - 1);
        int t0 = tokens[b * S_ + j];
        int t1 = tokens[b * S_ + j + 1];
        float ts0 = (t0 >= 256 && t0 < 768) ? 1.0f : 0.0f;
        float ts1 = (t1 >= 256 && t1 < 768) ? 1.0f : 0.0f;
        float rhythm = fabsf(ts1 - ts0);
        int p0 = (t0 < 128) ? t0 : 0;
        int p1 = (t1 < 128) ? t1 : 0;
        int iv = abs(p0 % 12 - p1 % 12);
        float harsh = (iv == 6 || iv == 11) ? 1.0f : 0.0f;
        float mel = (abs(p1 - p0) > 12) ? 1.0f : 0.0f;
        acc += rhythm * (1.0f / (float)NPAIR)
             + harsh * (1.0f / ((float)B_ * (float)S_))
             + mel * (1.0f / (float)NPAIR);
    }

    if (gid < B_ * S_)   acc += 0.4f * softplus_neg(local_logits[gid])  / (float)(B_ * S_);
    if (gid < B_ * P_)   acc += 0.4f * softplus_neg(phrase_logits[gid]) / (float)(B_ * P_);
    if (gid < B_)        acc += 0.2f * softplus_neg(global_logits[gid]) / (float)B_;

    #pragma unroll
    for (int off = 32; off > 0; off >>= 1)
        acc += __shfl_xor(acc, off, 64);

    __shared__ float warp_sums[4];
    int wid = threadIdx.x >> 6;
    int lane = threadIdx.x & 63;
    if (lane == 0) warp_sums[wid] = acc;
    __syncthreads();
    if (threadIdx.x == 0) {
        float t = warp_sums[0] + warp_sums[1] + warp_sums[2] + warp_sums[3];
        atomicAdd(out, t);
    }
}

extern "C" void kernel_launch(void* const* d_in, const int* in_sizes, int n_in,
                              void* d_out, int out_size, void* d_ws, size_t ws_size,
                              hipStream_t stream) {
    const float* real_local   = (const float*)d_in[0];
    const float* real_phrase  = (const float*)d_in[1];
    const float* real_global  = (const float*)d_in[2];
    const float* real_input   = (const float*)d_in[3];
    const float* fake_local   = (const float*)d_in[4];
    const float* fake_phrase  = (const float*)d_in[5];
    const float* fake_global  = (const float*)d_in[6];
    const float* fake_input   = (const float*)d_in[7];
    const float* local_logits  = (const float*)d_in[8];
    const float* phrase_logits = (const float*)d_in[9];
    const float* global_logits = (const float*)d_in[10];
    const int*   tokens        = (const int*)d_in[11];
    float* out = (float*)d_out;

    zero_out_kernel<<<1, 64, 0, stream>>>(out);

    fm_stream<<<NTASK, 256, 0, stream>>>(
        real_local, real_phrase, real_global, real_input,
        fake_local, fake_phrase, fake_global, fake_input, out);

    small_kernel<<<(B_ * S_) / 256, 256, 0, stream>>>(
        local_logits, phrase_logits, global_logits, tokens, out);
}